// Round 1
// baseline (806.117 us; speedup 1.0000x reference)
//
#include <hip/hip_runtime.h>
#include <math.h>

// GCN: 4x GCNConv (with self-loops, sym-norm) + BN+GELU between, log_softmax at end.
// Strategy: build CSR (grouped by dst) once per call, aggregate via gather (no atomics
// in the hot loops), exploit linearity to aggregate on the narrow side of each layer.

#define TPB 256
constexpr float BN_EPS = 1e-5f;

__global__ void setup_kernel(int* __restrict__ cnt, int* __restrict__ cursor,
                             float* __restrict__ stats, int n) {
    int i = blockIdx.x * blockDim.x + threadIdx.x;
    if (i < n) { cnt[i] = 0; cursor[i] = 0; }
    if (i < 384) stats[i] = 0.0f;
}

__global__ void count_kernel(const int* __restrict__ dst, int* __restrict__ cnt, int e) {
    int i = blockIdx.x * blockDim.x + threadIdx.x;
    if (i < e) atomicAdd(&cnt[dst[i]], 1);
}

__global__ void dinv_kernel(const int* __restrict__ cnt, float* __restrict__ dinv, int n) {
    int i = blockIdx.x * blockDim.x + threadIdx.x;
    if (i < n) dinv[i] = rsqrtf((float)(cnt[i] + 1));  // +1 = self loop
}

// Single-block exclusive scan of cnt[0..n) -> offsets[0..n]
__global__ void scan_kernel(const int* __restrict__ cnt, int* __restrict__ offsets, int n) {
    __shared__ int ssum[1024];
    __shared__ int carry;
    int tid = threadIdx.x;
    if (tid == 0) carry = 0;
    __syncthreads();
    for (int base = 0; base < n; base += 1024) {
        int i = base + tid;
        int c = (i < n) ? cnt[i] : 0;
        ssum[tid] = c;
        __syncthreads();
        for (int off = 1; off < 1024; off <<= 1) {
            int v = (tid >= off) ? ssum[tid - off] : 0;
            __syncthreads();
            ssum[tid] += v;
            __syncthreads();
        }
        int incl = ssum[tid];
        if (i < n) offsets[i] = carry + incl - c;
        int total = ssum[1023];
        __syncthreads();
        if (tid == 0) carry += total;
        __syncthreads();
    }
    if (tid == 0) offsets[n] = carry;
}

__global__ void fill_kernel(const int* __restrict__ src, const int* __restrict__ dst,
                            const float* __restrict__ dinv, const int* __restrict__ offsets,
                            int* __restrict__ cursor, int* __restrict__ csr_src,
                            float* __restrict__ csr_w, int e) {
    int i = blockIdx.x * blockDim.x + threadIdx.x;
    if (i >= e) return;
    int s = src[i], d = dst[i];
    int p = atomicAdd(&cursor[d], 1);
    int idx = offsets[d] + p;
    csr_src[idx] = s;
    csr_w[idx] = dinv[s] * dinv[d];
}

// T[n,FIN] @ W[FIN,FOUT] -> O[n,FOUT]. W staged in LDS; 1 thread per output elem.
template <int FIN, int FOUT>
__global__ void gemm_kernel(const float* __restrict__ H, const float* __restrict__ W,
                            float* __restrict__ O, int n) {
    __shared__ float Ws[FIN * FOUT];
    for (int i = threadIdx.x; i < FIN * FOUT; i += blockDim.x) Ws[i] = W[i];
    __syncthreads();
    int gid = blockIdx.x * blockDim.x + threadIdx.x;
    int row = gid / FOUT;
    int col = gid % FOUT;
    if (row >= n) return;
    const float* h = H + (size_t)row * FIN;
    float acc = 0.0f;
#pragma unroll
    for (int k = 0; k < FIN; ++k) acc = fmaf(h[k], Ws[k * FOUT + col], acc);
    O[gid] = acc;
}

// Gather-aggregate, F % 4 == 0: F/4 lanes per node, float4 per lane.
// acc init = self-loop term t[i] * dinv[i]^2.
template <int F>
__global__ void agg4_kernel(const float* __restrict__ T, float* __restrict__ A,
                            const float* __restrict__ dinv, const int* __restrict__ offsets,
                            const int* __restrict__ csr_src, const float* __restrict__ csr_w,
                            int n) {
    constexpr int G = F / 4;
    int idx = blockIdx.x * blockDim.x + threadIdx.x;
    int node = idx / G;
    int lane = idx % G;
    if (node >= n) return;
    const float4* T4 = (const float4*)T;
    float di = dinv[node];
    float w0 = di * di;
    float4 v = T4[(size_t)node * G + lane];
    float4 acc;
    acc.x = v.x * w0; acc.y = v.y * w0; acc.z = v.z * w0; acc.w = v.w * w0;
    int s = offsets[node], e = offsets[node + 1];
    for (int j = s; j < e; ++j) {
        int u = csr_src[j];
        float w = csr_w[j];
        float4 t = T4[(size_t)u * G + lane];
        acc.x = fmaf(t.x, w, acc.x);
        acc.y = fmaf(t.y, w, acc.y);
        acc.z = fmaf(t.z, w, acc.z);
        acc.w = fmaf(t.w, w, acc.w);
    }
    ((float4*)A)[(size_t)node * G + lane] = acc;
}

// Scalar variant for F=10 (G=16 lanes, 6 idle).
template <int F, int G>
__global__ void aggs_kernel(const float* __restrict__ T, float* __restrict__ A,
                            const float* __restrict__ dinv, const int* __restrict__ offsets,
                            const int* __restrict__ csr_src, const float* __restrict__ csr_w,
                            int n) {
    int idx = blockIdx.x * blockDim.x + threadIdx.x;
    int node = idx / G;
    int lane = idx % G;
    if (node >= n) return;
    float di = dinv[node];
    float acc = 0.0f;
    if (lane < F) acc = T[(size_t)node * F + lane] * di * di;
    int s = offsets[node], e = offsets[node + 1];
    for (int j = s; j < e; ++j) {
        int u = csr_src[j];
        float w = csr_w[j];
        if (lane < F) acc = fmaf(T[(size_t)u * F + lane], w, acc);
    }
    if (lane < F) A[(size_t)node * F + lane] = acc;
}

// Per-feature sum & sumsq, block-local LDS reduce then 2F global atomics per block.
template <int F>
__global__ void bn_stats_kernel(const float* __restrict__ V, float* __restrict__ stats, int n) {
    constexpr int RPB = TPB / F;
    int f = threadIdx.x % F;
    int rl = threadIdx.x / F;
    float s = 0.0f, s2 = 0.0f;
    for (int r = blockIdx.x * RPB + rl; r < n; r += gridDim.x * RPB) {
        float v = V[(size_t)r * F + f];
        s += v;
        s2 = fmaf(v, v, s2);
    }
    __shared__ float sh[2 * F];
    if (threadIdx.x < 2 * F) sh[threadIdx.x] = 0.0f;
    __syncthreads();
    atomicAdd(&sh[f], s);
    atomicAdd(&sh[F + f], s2);
    __syncthreads();
    if (threadIdx.x < 2 * F) atomicAdd(&stats[threadIdx.x], sh[threadIdx.x]);
}

// In-place BN (batch stats, biased var) + exact GELU. Conv bias cancels in BN.
template <int F>
__global__ void bn_gelu_kernel(float* __restrict__ V, const float* __restrict__ stats,
                               const float* __restrict__ g, const float* __restrict__ be,
                               int n) {
    int i = blockIdx.x * blockDim.x + threadIdx.x;
    if (i >= n * F) return;
    int f = i % F;
    float inv_n = 1.0f / (float)n;
    float mu = stats[f] * inv_n;
    float var = stats[F + f] * inv_n - mu * mu;
    float sc = rsqrtf(var + BN_EPS) * g[f];
    float sh = be[f] - mu * sc;
    float x = fmaf(V[i], sc, sh);
    V[i] = 0.5f * x * (1.0f + erff(x * 0.70710678118654752f));
}

__global__ void lsm_kernel(const float* __restrict__ A, const float* __restrict__ b4,
                           float* __restrict__ out, int n) {
    int r = blockIdx.x * blockDim.x + threadIdx.x;
    if (r >= n) return;
    float v[10];
    float m = -1e30f;
#pragma unroll
    for (int c = 0; c < 10; ++c) {
        v[c] = A[(size_t)r * 10 + c] + b4[c];
        m = fmaxf(m, v[c]);
    }
    float s = 0.0f;
#pragma unroll
    for (int c = 0; c < 10; ++c) s += expf(v[c] - m);
    float ls = logf(s) + m;
#pragma unroll
    for (int c = 0; c < 10; ++c) out[(size_t)r * 10 + c] = v[c] - ls;
}

static inline int cdiv(long long a, int b) { return (int)((a + b - 1) / b); }

extern "C" void kernel_launch(void* const* d_in, const int* in_sizes, int n_in,
                              void* d_out, int out_size, void* d_ws, size_t ws_size,
                              hipStream_t stream) {
    const float* x  = (const float*)d_in[0];
    const int*   ei = (const int*)d_in[1];
    const float* W1 = (const float*)d_in[2];
    const float* g1 = (const float*)d_in[4];
    const float* be1= (const float*)d_in[5];
    const float* W2 = (const float*)d_in[6];
    const float* g2 = (const float*)d_in[8];
    const float* be2= (const float*)d_in[9];
    const float* W3 = (const float*)d_in[10];
    const float* g3 = (const float*)d_in[12];
    const float* be3= (const float*)d_in[13];
    const float* W4 = (const float*)d_in[14];
    const float* b4 = (const float*)d_in[15];
    float* out = (float*)d_out;

    const int N = in_sizes[0] / 128;
    const int E = in_sizes[1] / 2;
    const int* srcI = ei;
    const int* dstI = ei + E;

    char* p = (char*)d_ws;
    auto carve = [&](size_t bytes) {
        void* q = (void*)p;
        p += (bytes + 255) & ~(size_t)255;
        return q;
    };
    int*   cnt     = (int*)  carve((size_t)N * 4);
    int*   cursor  = (int*)  carve((size_t)N * 4);
    int*   offsets = (int*)  carve((size_t)(N + 1) * 4);
    float* dinv    = (float*)carve((size_t)N * 4);
    int*   csr_src = (int*)  carve((size_t)E * 4);
    float* csr_w   = (float*)carve((size_t)E * 4);
    float* stats   = (float*)carve(384 * 4);   // 3 layers x 128 (sum|sumsq)
    float* A       = (float*)carve((size_t)N * 64 * 4);
    float* B       = (float*)carve((size_t)N * 64 * 4);

    // --- CSR build ---
    setup_kernel<<<cdiv(N, TPB), TPB, 0, stream>>>(cnt, cursor, stats, N);
    count_kernel<<<cdiv(E, TPB), TPB, 0, stream>>>(dstI, cnt, E);
    dinv_kernel<<<cdiv(N, TPB), TPB, 0, stream>>>(cnt, dinv, N);
    scan_kernel<<<1, 1024, 0, stream>>>(cnt, offsets, N);
    fill_kernel<<<cdiv(E, TPB), TPB, 0, stream>>>(srcI, dstI, dinv, offsets, cursor,
                                                  csr_src, csr_w, E);

    // --- L1: transform(128->16) then aggregate(16) ---
    gemm_kernel<128, 16><<<cdiv((long long)N * 16, TPB), TPB, 0, stream>>>(x, W1, A, N);
    agg4_kernel<16><<<cdiv((long long)N * 4, TPB), TPB, 0, stream>>>(A, B, dinv, offsets, csr_src, csr_w, N);
    bn_stats_kernel<16><<<256, TPB, 0, stream>>>(B, stats + 0, N);
    bn_gelu_kernel<16><<<cdiv((long long)N * 16, TPB), TPB, 0, stream>>>(B, stats + 0, g1, be1, N);

    // --- L2: aggregate(16) then transform(16->32) ---
    agg4_kernel<16><<<cdiv((long long)N * 4, TPB), TPB, 0, stream>>>(B, A, dinv, offsets, csr_src, csr_w, N);
    gemm_kernel<16, 32><<<cdiv((long long)N * 32, TPB), TPB, 0, stream>>>(A, W2, B, N);
    bn_stats_kernel<32><<<256, TPB, 0, stream>>>(B, stats + 128, N);
    bn_gelu_kernel<32><<<cdiv((long long)N * 32, TPB), TPB, 0, stream>>>(B, stats + 128, g2, be2, N);

    // --- L3: aggregate(32) then transform(32->64) ---
    agg4_kernel<32><<<cdiv((long long)N * 8, TPB), TPB, 0, stream>>>(B, A, dinv, offsets, csr_src, csr_w, N);
    gemm_kernel<32, 64><<<cdiv((long long)N * 64, TPB), TPB, 0, stream>>>(A, W3, B, N);
    bn_stats_kernel<64><<<256, TPB, 0, stream>>>(B, stats + 256, N);
    bn_gelu_kernel<64><<<cdiv((long long)N * 64, TPB), TPB, 0, stream>>>(B, stats + 256, g3, be3, N);

    // --- L4: transform(64->10) then aggregate(10), +b4, log_softmax ---
    gemm_kernel<64, 10><<<cdiv((long long)N * 10, TPB), TPB, 0, stream>>>(B, W4, A, N);
    aggs_kernel<10, 16><<<cdiv((long long)N * 16, TPB), TPB, 0, stream>>>(A, B, dinv, offsets, csr_src, csr_w, N);
    lsm_kernel<<<cdiv(N, TPB), TPB, 0, stream>>>(B, b4, out, N);
}

// Round 4
// 621.890 us; speedup vs baseline: 1.2962x; 1.2962x over previous
//
#include <hip/hip_runtime.h>
#include <math.h>

// GCN: 4x GCNConv (self-loops, sym-norm) + BN+GELU between, log_softmax at end.
// CSR (by dst) built per call; aggregation = atomic-free gather; aggregate on the
// narrow side of each layer (linearity); BN bias-cancellation drops b1..b3.
// R1: hierarchical scan (was 177us single-block), BN-stats fused into producer
// epilogues, csr_w dropped (recompute from dinv), log_softmax fused into last agg.
// R2/R3: resubmits of R1 (infra failures, no measurement).

#define TPB 256
constexpr float BN_EPS = 1e-5f;

// ---------------- CSR build ----------------

__global__ void setup_kernel(int* __restrict__ cnt, int* __restrict__ cursor,
                             float* __restrict__ stats, int n) {
    int i = blockIdx.x * blockDim.x + threadIdx.x;
    if (i < n) { cnt[i] = 0; cursor[i] = 0; }
    if (i < 384) stats[i] = 0.0f;
}

__global__ void count_kernel(const int* __restrict__ dst, int* __restrict__ cnt, int e) {
    int i = blockIdx.x * blockDim.x + threadIdx.x;
    if (i < e) atomicAdd(&cnt[dst[i]], 1);
}

#define SCHUNK 2048  // elements per scan block (256 thr x 8)

__global__ void scan_reduce_kernel(const int* __restrict__ cnt, int* __restrict__ bsum, int n) {
    int base = blockIdx.x * SCHUNK;
    int s = 0;
    for (int j = threadIdx.x; j < SCHUNK; j += TPB) {
        int i = base + j;
        s += (i < n) ? cnt[i] : 0;
    }
#pragma unroll
    for (int d = 32; d; d >>= 1) s += __shfl_down(s, d);
    __shared__ int ws[TPB / 64];
    if ((threadIdx.x & 63) == 0) ws[threadIdx.x >> 6] = s;
    __syncthreads();
    if (threadIdx.x == 0) {
        int t = 0;
        for (int w = 0; w < TPB / 64; ++w) t += ws[w];
        bsum[blockIdx.x] = t;
    }
}

// single wave: exclusive-scan bsum[0..nb), write grand total to offsets[n]
__global__ void scan_bsum_kernel(int* __restrict__ bsum, int* __restrict__ offsets,
                                 int nb, int n) {
    __shared__ int carry;
    int lane = threadIdx.x;
    if (lane == 0) carry = 0;
    __syncthreads();
    for (int base = 0; base < nb; base += 64) {
        int i = base + lane;
        int v = (i < nb) ? bsum[i] : 0;
        int incl = v;
#pragma unroll
        for (int d = 1; d < 64; d <<= 1) {
            int u = __shfl_up(incl, d);
            if (lane >= d) incl += u;
        }
        if (i < nb) bsum[i] = carry + incl - v;
        int tot = __shfl(incl, 63);
        __syncthreads();
        if (lane == 0) carry += tot;
        __syncthreads();
    }
    if (lane == 0) offsets[n] = carry;
}

// block-local scan + apply block prefix; also computes dinv (cnt already in regs)
__global__ void scan_apply_kernel(const int* __restrict__ cnt, const int* __restrict__ bsum,
                                  int* __restrict__ offsets, float* __restrict__ dinv, int n) {
    int base = blockIdx.x * SCHUNK;
    int tid = threadIdx.x;
    int lane = tid & 63, wave = tid >> 6;
    int i0 = base + tid * 8;
    int v[8];
    int tsum = 0;
#pragma unroll
    for (int k = 0; k < 8; ++k) {
        int i = i0 + k;
        v[k] = (i < n) ? cnt[i] : 0;
        tsum += v[k];
    }
    int incl = tsum;
#pragma unroll
    for (int d = 1; d < 64; d <<= 1) {
        int u = __shfl_up(incl, d);
        if (lane >= d) incl += u;
    }
    int lexcl = incl - tsum;
    __shared__ int wsum[TPB / 64];
    if (lane == 63) wsum[wave] = incl;
    __syncthreads();
    int wbase = 0;
    for (int w = 0; w < wave; ++w) wbase += wsum[w];
    int off = bsum[blockIdx.x] + wbase + lexcl;
#pragma unroll
    for (int k = 0; k < 8; ++k) {
        int i = i0 + k;
        if (i < n) {
            offsets[i] = off;
            dinv[i] = rsqrtf((float)(v[k] + 1));  // +1 = self loop
        }
        off += v[k];
    }
}

__global__ void fill_kernel(const int* __restrict__ src, const int* __restrict__ dst,
                            const int* __restrict__ offsets, int* __restrict__ cursor,
                            int* __restrict__ csr_src, int e) {
    int i = blockIdx.x * blockDim.x + threadIdx.x;
    if (i >= e) return;
    int s = src[i], d = dst[i];
    int p = atomicAdd(&cursor[d], 1);
    csr_src[offsets[d] + p] = s;
}

// ---------------- dense transforms ----------------

// Grid-stride H[n,FIN] @ W[FIN,FOUT] -> O[n,FOUT]; optional fused BN-stats.
// col per thread is loop-invariant because stride(=grid*TPB) % FOUT == 0.
template <int FIN, int FOUT, bool STATS>
__global__ void gemm_kernel(const float* __restrict__ H, const float* __restrict__ W,
                            float* __restrict__ O, float* __restrict__ stats, int n) {
    __shared__ float Ws[FIN * FOUT];
    __shared__ float sh[STATS ? 2 * FOUT : 1];
    for (int i = threadIdx.x; i < FIN * FOUT; i += blockDim.x) Ws[i] = W[i];
    if (STATS)
        for (int i = threadIdx.x; i < 2 * FOUT; i += blockDim.x) sh[i] = 0.0f;
    __syncthreads();
    long long total = (long long)n * FOUT;
    long long stride = (long long)gridDim.x * blockDim.x;
    float s = 0.0f, s2 = 0.0f;
    int col0 = -1;
    for (long long gid = (long long)blockIdx.x * blockDim.x + threadIdx.x; gid < total;
         gid += stride) {
        int row = (int)(gid / FOUT);
        int col = (int)(gid % FOUT);
        const float* h = H + (size_t)row * FIN;
        float acc = 0.0f;
#pragma unroll
        for (int k = 0; k < FIN; ++k) acc = fmaf(h[k], Ws[k * FOUT + col], acc);
        O[gid] = acc;
        if (STATS) { s += acc; s2 = fmaf(acc, acc, s2); col0 = col; }
    }
    if (STATS) {
        if (col0 >= 0) {
            atomicAdd(&sh[col0], s);
            atomicAdd(&sh[FOUT + col0], s2);
        }
        __syncthreads();
        for (int i = threadIdx.x; i < 2 * FOUT; i += blockDim.x) atomicAdd(&stats[i], sh[i]);
    }
}

// ---------------- aggregation ----------------

// Gather-aggregate, F%4==0: F/4 lanes/node, float4/lane; self-loop in init.
// w = dinv[u]*dinv[node] recomputed (dinv is 400KB -> L2-resident).
template <int F, bool STATS>
__global__ void agg4_kernel(const float* __restrict__ T, float* __restrict__ A,
                            const float* __restrict__ dinv, const int* __restrict__ offsets,
                            const int* __restrict__ csr_src, float* __restrict__ stats, int n) {
    constexpr int G = F / 4;
    __shared__ float sh[STATS ? 2 * F : 1];
    if (STATS) {
        for (int i = threadIdx.x; i < 2 * F; i += blockDim.x) sh[i] = 0.0f;
        __syncthreads();
    }
    const float4* T4 = (const float4*)T;
    float4 ss = {0, 0, 0, 0}, s2 = {0, 0, 0, 0};
    int lane0 = -1;
    int total = n * G;
    int stride = gridDim.x * blockDim.x;  // % G == 0 since TPB % G == 0
    for (int idx = blockIdx.x * blockDim.x + threadIdx.x; idx < total; idx += stride) {
        int node = idx / G;
        int lane = idx % G;
        float di = dinv[node];
        float w0 = di * di;
        float4 v = T4[(size_t)node * G + lane];
        float4 acc;
        acc.x = v.x * w0; acc.y = v.y * w0; acc.z = v.z * w0; acc.w = v.w * w0;
        int s = offsets[node], e = offsets[node + 1];
        for (int j = s; j < e; ++j) {
            int u = csr_src[j];
            float w = dinv[u] * di;
            float4 t = T4[(size_t)u * G + lane];
            acc.x = fmaf(t.x, w, acc.x);
            acc.y = fmaf(t.y, w, acc.y);
            acc.z = fmaf(t.z, w, acc.z);
            acc.w = fmaf(t.w, w, acc.w);
        }
        ((float4*)A)[(size_t)idx] = acc;
        if (STATS) {
            ss.x += acc.x; ss.y += acc.y; ss.z += acc.z; ss.w += acc.w;
            s2.x = fmaf(acc.x, acc.x, s2.x); s2.y = fmaf(acc.y, acc.y, s2.y);
            s2.z = fmaf(acc.z, acc.z, s2.z); s2.w = fmaf(acc.w, acc.w, s2.w);
            lane0 = lane;
        }
    }
    if (STATS) {
        if (lane0 >= 0) {
            atomicAdd(&sh[lane0 * 4 + 0], ss.x); atomicAdd(&sh[lane0 * 4 + 1], ss.y);
            atomicAdd(&sh[lane0 * 4 + 2], ss.z); atomicAdd(&sh[lane0 * 4 + 3], ss.w);
            atomicAdd(&sh[F + lane0 * 4 + 0], s2.x); atomicAdd(&sh[F + lane0 * 4 + 1], s2.y);
            atomicAdd(&sh[F + lane0 * 4 + 2], s2.z); atomicAdd(&sh[F + lane0 * 4 + 3], s2.w);
        }
        __syncthreads();
        for (int i = threadIdx.x; i < 2 * F; i += blockDim.x) atomicAdd(&stats[i], sh[i]);
    }
}

// Final layer: aggregate F=10 (16 lanes/node) + b4 + log_softmax via 16-lane shuffles.
__global__ void agg_lsm_kernel(const float* __restrict__ T, const float* __restrict__ dinv,
                               const int* __restrict__ offsets, const int* __restrict__ csr_src,
                               const float* __restrict__ b4, float* __restrict__ out, int n) {
    int idx = blockIdx.x * blockDim.x + threadIdx.x;
    int node = idx >> 4;
    int lane = idx & 15;
    if (node >= n) return;
    bool act = lane < 10;
    float di = dinv[node];
    float acc = 0.0f;
    if (act) acc = T[(size_t)node * 10 + lane] * di * di;
    int s = offsets[node], e = offsets[node + 1];
    for (int j = s; j < e; ++j) {
        int u = csr_src[j];
        float w = dinv[u] * di;
        if (act) acc = fmaf(T[(size_t)u * 10 + lane], w, acc);
    }
    float v = act ? acc + b4[lane] : -1e30f;
    float m = v;
#pragma unroll
    for (int d = 1; d < 16; d <<= 1) m = fmaxf(m, __shfl_xor(m, d));
    float ex = act ? expf(v - m) : 0.0f;
    float sum = ex;
#pragma unroll
    for (int d = 1; d < 16; d <<= 1) sum += __shfl_xor(sum, d);
    if (act) out[(size_t)node * 10 + lane] = v - m - logf(sum);
}

// ---------------- BN + GELU ----------------

template <int F>
__global__ void bn_gelu_kernel(float* __restrict__ V, const float* __restrict__ stats,
                               const float* __restrict__ g, const float* __restrict__ be,
                               int n) {
    int i = blockIdx.x * blockDim.x + threadIdx.x;
    if (i >= n * F) return;
    int f = i % F;
    float inv_n = 1.0f / (float)n;
    float mu = stats[f] * inv_n;
    float var = stats[F + f] * inv_n - mu * mu;
    float sc = rsqrtf(var + BN_EPS) * g[f];
    float sh = be[f] - mu * sc;
    float x = fmaf(V[i], sc, sh);
    V[i] = 0.5f * x * (1.0f + erff(x * 0.70710678118654752f));
}

static inline int cdiv(long long a, int b) { return (int)((a + b - 1) / b); }

extern "C" void kernel_launch(void* const* d_in, const int* in_sizes, int n_in,
                              void* d_out, int out_size, void* d_ws, size_t ws_size,
                              hipStream_t stream) {
    const float* x  = (const float*)d_in[0];
    const int*   ei = (const int*)d_in[1];
    const float* W1 = (const float*)d_in[2];
    const float* g1 = (const float*)d_in[4];
    const float* be1= (const float*)d_in[5];
    const float* W2 = (const float*)d_in[6];
    const float* g2 = (const float*)d_in[8];
    const float* be2= (const float*)d_in[9];
    const float* W3 = (const float*)d_in[10];
    const float* g3 = (const float*)d_in[12];
    const float* be3= (const float*)d_in[13];
    const float* W4 = (const float*)d_in[14];
    const float* b4 = (const float*)d_in[15];
    float* out = (float*)d_out;

    const int N = in_sizes[0] / 128;
    const int E = in_sizes[1] / 2;
    const int* srcI = ei;
    const int* dstI = ei + E;
    const int NB = cdiv(N, SCHUNK);

    char* p = (char*)d_ws;
    auto carve = [&](size_t bytes) {
        void* q = (void*)p;
        p += (bytes + 255) & ~(size_t)255;
        return q;
    };
    int*   cnt     = (int*)  carve((size_t)N * 4);
    int*   cursor  = (int*)  carve((size_t)N * 4);
    int*   offsets = (int*)  carve((size_t)(N + 1) * 4);
    float* dinv    = (float*)carve((size_t)N * 4);
    int*   csr_src = (int*)  carve((size_t)E * 4);
    int*   bsum    = (int*)  carve((size_t)(NB + 1) * 4);
    float* stats   = (float*)carve(384 * 4);   // L1@0 (2x16), L2@128 (2x32), L3@256 (2x64)
    float* A       = (float*)carve((size_t)N * 64 * 4);
    float* B       = (float*)carve((size_t)N * 64 * 4);

    // --- CSR build ---
    setup_kernel<<<cdiv(N, TPB), TPB, 0, stream>>>(cnt, cursor, stats, N);
    count_kernel<<<cdiv(E, TPB), TPB, 0, stream>>>(dstI, cnt, E);
    scan_reduce_kernel<<<NB, TPB, 0, stream>>>(cnt, bsum, N);
    scan_bsum_kernel<<<1, 64, 0, stream>>>(bsum, offsets, NB, N);
    scan_apply_kernel<<<NB, TPB, 0, stream>>>(cnt, bsum, offsets, dinv, N);
    fill_kernel<<<cdiv(E, TPB), TPB, 0, stream>>>(srcI, dstI, offsets, cursor, csr_src, E);

    // --- L1: transform(128->16) then aggregate(16) [stats fused into agg] ---
    gemm_kernel<128, 16, false><<<1024, TPB, 0, stream>>>(x, W1, A, nullptr, N);
    agg4_kernel<16, true><<<512, TPB, 0, stream>>>(A, B, dinv, offsets, csr_src, stats + 0, N);
    bn_gelu_kernel<16><<<cdiv((long long)N * 16, TPB), TPB, 0, stream>>>(B, stats + 0, g1, be1, N);

    // --- L2: aggregate(16) then transform(16->32) [stats fused into gemm] ---
    agg4_kernel<16, false><<<cdiv((long long)N * 4, TPB), TPB, 0, stream>>>(B, A, dinv, offsets, csr_src, nullptr, N);
    gemm_kernel<16, 32, true><<<1024, TPB, 0, stream>>>(A, W2, B, stats + 128, N);
    bn_gelu_kernel<32><<<cdiv((long long)N * 32, TPB), TPB, 0, stream>>>(B, stats + 128, g2, be2, N);

    // --- L3: aggregate(32) then transform(32->64) [stats fused into gemm] ---
    agg4_kernel<32, false><<<cdiv((long long)N * 8, TPB), TPB, 0, stream>>>(B, A, dinv, offsets, csr_src, nullptr, N);
    gemm_kernel<32, 64, true><<<1024, TPB, 0, stream>>>(A, W3, B, stats + 256, N);
    bn_gelu_kernel<64><<<cdiv((long long)N * 64, TPB), TPB, 0, stream>>>(B, stats + 256, g3, be3, N);

    // --- L4: transform(64->10) then aggregate(10)+b4+log_softmax ---
    gemm_kernel<64, 10, false><<<1024, TPB, 0, stream>>>(B, W4, A, nullptr, N);
    agg_lsm_kernel<<<cdiv((long long)N * 16, TPB), TPB, 0, stream>>>(A, dinv, offsets, csr_src, b4, out, N);
}

// Round 6
// 552.719 us; speedup vs baseline: 1.4585x; 1.1251x over previous
//
#include <hip/hip_runtime.h>
#include <math.h>

// GCN: 4x GCNConv (self-loops, sym-norm) + BN+GELU between, log_softmax at end.
// CSR (by dst) built per call; aggregation = atomic-free gather; aggregate on the
// narrow side of each layer (linearity); BN bias-cancellation drops b1..b3.
// R1: hierarchical scan, fused BN-stats, fused log_softmax. 806 -> 622 us.
// R4: (a) dst-windowed fill (fill WRITE_SIZE was 107MB for a 6.4MB buffer = 16x
//     partial-line writeback amplification; 4 dst-windows keep the 1.6MB window
//     L2-resident so lines fill before eviction); (b) dinv-prescale in producer
//     epilogues => agg inner loop is pure gather+add (no dinv[u] gather, no mul);
//     (c) unroll-by-4 gather loop for 4 outstanding loads.
// R5: resubmit of R4 (broker timeout, no measurement).

#define TPB 256
constexpr float BN_EPS = 1e-5f;

// ---------------- CSR build ----------------

__global__ void setup_kernel(int* __restrict__ cnt, int* __restrict__ cursor,
                             float* __restrict__ stats, int n) {
    int i = blockIdx.x * blockDim.x + threadIdx.x;
    if (i < n) { cnt[i] = 0; cursor[i] = 0; }
    if (i < 384) stats[i] = 0.0f;
}

__global__ void count_kernel(const int* __restrict__ dst, int* __restrict__ cnt, int e) {
    int i = blockIdx.x * blockDim.x + threadIdx.x;
    if (i < e) atomicAdd(&cnt[dst[i]], 1);
}

#define SCHUNK 2048  // elements per scan block (256 thr x 8)

__global__ void scan_reduce_kernel(const int* __restrict__ cnt, int* __restrict__ bsum, int n) {
    int base = blockIdx.x * SCHUNK;
    int s = 0;
    for (int j = threadIdx.x; j < SCHUNK; j += TPB) {
        int i = base + j;
        s += (i < n) ? cnt[i] : 0;
    }
#pragma unroll
    for (int d = 32; d; d >>= 1) s += __shfl_down(s, d);
    __shared__ int ws[TPB / 64];
    if ((threadIdx.x & 63) == 0) ws[threadIdx.x >> 6] = s;
    __syncthreads();
    if (threadIdx.x == 0) {
        int t = 0;
        for (int w = 0; w < TPB / 64; ++w) t += ws[w];
        bsum[blockIdx.x] = t;
    }
}

// single wave: exclusive-scan bsum[0..nb), write grand total to offsets[n]
__global__ void scan_bsum_kernel(int* __restrict__ bsum, int* __restrict__ offsets,
                                 int nb, int n) {
    __shared__ int carry;
    int lane = threadIdx.x;
    if (lane == 0) carry = 0;
    __syncthreads();
    for (int base = 0; base < nb; base += 64) {
        int i = base + lane;
        int v = (i < nb) ? bsum[i] : 0;
        int incl = v;
#pragma unroll
        for (int d = 1; d < 64; d <<= 1) {
            int u = __shfl_up(incl, d);
            if (lane >= d) incl += u;
        }
        if (i < nb) bsum[i] = carry + incl - v;
        int tot = __shfl(incl, 63);
        __syncthreads();
        if (lane == 0) carry += tot;
        __syncthreads();
    }
    if (lane == 0) offsets[n] = carry;
}

// block-local scan + apply block prefix; also computes dinv (cnt already in regs)
__global__ void scan_apply_kernel(const int* __restrict__ cnt, const int* __restrict__ bsum,
                                  int* __restrict__ offsets, float* __restrict__ dinv, int n) {
    int base = blockIdx.x * SCHUNK;
    int tid = threadIdx.x;
    int lane = tid & 63, wave = tid >> 6;
    int i0 = base + tid * 8;
    int v[8];
    int tsum = 0;
#pragma unroll
    for (int k = 0; k < 8; ++k) {
        int i = i0 + k;
        v[k] = (i < n) ? cnt[i] : 0;
        tsum += v[k];
    }
    int incl = tsum;
#pragma unroll
    for (int d = 1; d < 64; d <<= 1) {
        int u = __shfl_up(incl, d);
        if (lane >= d) incl += u;
    }
    int lexcl = incl - tsum;
    __shared__ int wsum[TPB / 64];
    if (lane == 63) wsum[wave] = incl;
    __syncthreads();
    int wbase = 0;
    for (int w = 0; w < wave; ++w) wbase += wsum[w];
    int off = bsum[blockIdx.x] + wbase + lexcl;
#pragma unroll
    for (int k = 0; k < 8; ++k) {
        int i = i0 + k;
        if (i < n) {
            offsets[i] = off;
            dinv[i] = rsqrtf((float)(v[k] + 1));  // +1 = self loop
        }
        off += v[k];
    }
}

// dst-windowed CSR fill: pass p only places dst in [p*n/NP,(p+1)*n/NP), so the
// active csr_src window (~E/NP*4B = 1.6MB) stays L2-resident and lines accumulate
// all their slots before writeback (kills 16x partial-line amplification).
__global__ void fill_kernel(const int* __restrict__ src, const int* __restrict__ dst,
                            const int* __restrict__ offsets, int* __restrict__ cursor,
                            int* __restrict__ csr_src, int e, int n) {
    constexpr int NP = 4;
    int stride = gridDim.x * blockDim.x;
    for (int p = 0; p < NP; ++p) {
        int lo = (int)((long long)n * p / NP);
        int hi = (int)((long long)n * (p + 1) / NP);
        for (int i = blockIdx.x * blockDim.x + threadIdx.x; i < e; i += stride) {
            int d = dst[i];
            if (d >= lo && d < hi) {
                int pos = atomicAdd(&cursor[d], 1);
                csr_src[offsets[d] + pos] = src[i];
            }
        }
    }
}

// ---------------- dense transforms ----------------

// Grid-stride H[n,FIN] @ W[FIN,FOUT] -> O[n,FOUT]; optional fused BN-stats
// (on unscaled output) and optional output prescale by dinv[row] (for next agg).
// col per thread is loop-invariant because stride % FOUT == 0.
template <int FIN, int FOUT, bool STATS, bool DINV>
__global__ void gemm_kernel(const float* __restrict__ H, const float* __restrict__ W,
                            float* __restrict__ O, float* __restrict__ stats,
                            const float* __restrict__ dinv, int n) {
    __shared__ float Ws[FIN * FOUT];
    __shared__ float sh[STATS ? 2 * FOUT : 1];
    for (int i = threadIdx.x; i < FIN * FOUT; i += blockDim.x) Ws[i] = W[i];
    if (STATS)
        for (int i = threadIdx.x; i < 2 * FOUT; i += blockDim.x) sh[i] = 0.0f;
    __syncthreads();
    long long total = (long long)n * FOUT;
    long long stride = (long long)gridDim.x * blockDim.x;
    float s = 0.0f, s2 = 0.0f;
    int col0 = -1;
    for (long long gid = (long long)blockIdx.x * blockDim.x + threadIdx.x; gid < total;
         gid += stride) {
        int row = (int)(gid / FOUT);
        int col = (int)(gid % FOUT);
        const float* h = H + (size_t)row * FIN;
        float acc = 0.0f;
#pragma unroll
        for (int k = 0; k < FIN; ++k) acc = fmaf(h[k], Ws[k * FOUT + col], acc);
        if (STATS) { s += acc; s2 = fmaf(acc, acc, s2); col0 = col; }
        O[gid] = DINV ? acc * dinv[row] : acc;
    }
    if (STATS) {
        if (col0 >= 0) {
            atomicAdd(&sh[col0], s);
            atomicAdd(&sh[FOUT + col0], s2);
        }
        __syncthreads();
        for (int i = threadIdx.x; i < 2 * FOUT; i += blockDim.x) atomicAdd(&stats[i], sh[i]);
    }
}

// ---------------- aggregation ----------------

// Gather-aggregate over dinv-PRESCALED table T' (T'[u] = T[u]*dinv[u]):
//   out[node] = dinv[node] * (sum_{u in nbr} T'[u] + T'[node])
// Inner loop is pure gather+add, unrolled x4 for MLP. F%4==0: F/4 lanes/node.
template <int F, bool STATS>
__global__ void agg4_kernel(const float* __restrict__ T, float* __restrict__ A,
                            const float* __restrict__ dinv, const int* __restrict__ offsets,
                            const int* __restrict__ csr_src, float* __restrict__ stats, int n) {
    constexpr int G = F / 4;
    __shared__ float sh[STATS ? 2 * F : 1];
    if (STATS) {
        for (int i = threadIdx.x; i < 2 * F; i += blockDim.x) sh[i] = 0.0f;
        __syncthreads();
    }
    const float4* T4 = (const float4*)T;
    float4 ss = {0, 0, 0, 0}, s2 = {0, 0, 0, 0};
    int lane0 = -1;
    int total = n * G;
    int stride = gridDim.x * blockDim.x;  // % G == 0 since TPB % G == 0
    for (int idx = blockIdx.x * blockDim.x + threadIdx.x; idx < total; idx += stride) {
        int node = idx / G;
        int lane = idx % G;
        float4 acc = T4[(size_t)node * G + lane];  // self term (prescaled)
        int s = offsets[node], e = offsets[node + 1];
        int j = s;
        for (; j + 3 < e; j += 4) {
            int u0 = csr_src[j], u1 = csr_src[j + 1], u2 = csr_src[j + 2], u3 = csr_src[j + 3];
            float4 t0 = T4[(size_t)u0 * G + lane];
            float4 t1 = T4[(size_t)u1 * G + lane];
            float4 t2 = T4[(size_t)u2 * G + lane];
            float4 t3 = T4[(size_t)u3 * G + lane];
            acc.x += (t0.x + t1.x) + (t2.x + t3.x);
            acc.y += (t0.y + t1.y) + (t2.y + t3.y);
            acc.z += (t0.z + t1.z) + (t2.z + t3.z);
            acc.w += (t0.w + t1.w) + (t2.w + t3.w);
        }
        for (; j < e; ++j) {
            int u = csr_src[j];
            float4 t = T4[(size_t)u * G + lane];
            acc.x += t.x; acc.y += t.y; acc.z += t.z; acc.w += t.w;
        }
        float di = dinv[node];
        acc.x *= di; acc.y *= di; acc.z *= di; acc.w *= di;
        ((float4*)A)[(size_t)idx] = acc;
        if (STATS) {
            ss.x += acc.x; ss.y += acc.y; ss.z += acc.z; ss.w += acc.w;
            s2.x = fmaf(acc.x, acc.x, s2.x); s2.y = fmaf(acc.y, acc.y, s2.y);
            s2.z = fmaf(acc.z, acc.z, s2.z); s2.w = fmaf(acc.w, acc.w, s2.w);
            lane0 = lane;
        }
    }
    if (STATS) {
        if (lane0 >= 0) {
            atomicAdd(&sh[lane0 * 4 + 0], ss.x); atomicAdd(&sh[lane0 * 4 + 1], ss.y);
            atomicAdd(&sh[lane0 * 4 + 2], ss.z); atomicAdd(&sh[lane0 * 4 + 3], ss.w);
            atomicAdd(&sh[F + lane0 * 4 + 0], s2.x); atomicAdd(&sh[F + lane0 * 4 + 1], s2.y);
            atomicAdd(&sh[F + lane0 * 4 + 2], s2.z); atomicAdd(&sh[F + lane0 * 4 + 3], s2.w);
        }
        __syncthreads();
        for (int i = threadIdx.x; i < 2 * F; i += blockDim.x) atomicAdd(&stats[i], sh[i]);
    }
}

// Final layer: aggregate prescaled F=10 (16 lanes/node) + b4 + log_softmax.
__global__ void agg_lsm_kernel(const float* __restrict__ T, const float* __restrict__ dinv,
                               const int* __restrict__ offsets, const int* __restrict__ csr_src,
                               const float* __restrict__ b4, float* __restrict__ out, int n) {
    int idx = blockIdx.x * blockDim.x + threadIdx.x;
    int node = idx >> 4;
    int lane = idx & 15;
    if (node >= n) return;
    bool act = lane < 10;
    float acc = act ? T[(size_t)node * 10 + lane] : 0.0f;  // self (prescaled)
    int s = offsets[node], e = offsets[node + 1];
    int j = s;
    for (; j + 1 < e; j += 2) {
        int u0 = csr_src[j], u1 = csr_src[j + 1];
        float t0 = act ? T[(size_t)u0 * 10 + lane] : 0.0f;
        float t1 = act ? T[(size_t)u1 * 10 + lane] : 0.0f;
        acc += t0 + t1;
    }
    if (j < e) {
        int u = csr_src[j];
        if (act) acc += T[(size_t)u * 10 + lane];
    }
    float v = act ? fmaf(dinv[node], acc, b4[lane]) : -1e30f;
    float m = v;
#pragma unroll
    for (int d = 1; d < 16; d <<= 1) m = fmaxf(m, __shfl_xor(m, d));
    float ex = act ? expf(v - m) : 0.0f;
    float sum = ex;
#pragma unroll
    for (int d = 1; d < 16; d <<= 1) sum += __shfl_xor(sum, d);
    if (act) out[(size_t)node * 10 + lane] = v - m - logf(sum);
}

// ---------------- BN + GELU ----------------

// In-place BN (batch stats) + exact GELU; optional prescale by dinv (next-agg fusion).
template <int F, bool DINV>
__global__ void bn_gelu_kernel(float* __restrict__ V, const float* __restrict__ stats,
                               const float* __restrict__ g, const float* __restrict__ be,
                               const float* __restrict__ dinv, int n) {
    int i = blockIdx.x * blockDim.x + threadIdx.x;
    if (i >= n * F) return;
    int f = i % F;
    float inv_n = 1.0f / (float)n;
    float mu = stats[f] * inv_n;
    float var = stats[F + f] * inv_n - mu * mu;
    float sc = rsqrtf(var + BN_EPS) * g[f];
    float shf = be[f] - mu * sc;
    float x = fmaf(V[i], sc, shf);
    float y = 0.5f * x * (1.0f + erff(x * 0.70710678118654752f));
    V[i] = DINV ? y * dinv[i / F] : y;
}

static inline int cdiv(long long a, int b) { return (int)((a + b - 1) / b); }

extern "C" void kernel_launch(void* const* d_in, const int* in_sizes, int n_in,
                              void* d_out, int out_size, void* d_ws, size_t ws_size,
                              hipStream_t stream) {
    const float* x  = (const float*)d_in[0];
    const int*   ei = (const int*)d_in[1];
    const float* W1 = (const float*)d_in[2];
    const float* g1 = (const float*)d_in[4];
    const float* be1= (const float*)d_in[5];
    const float* W2 = (const float*)d_in[6];
    const float* g2 = (const float*)d_in[8];
    const float* be2= (const float*)d_in[9];
    const float* W3 = (const float*)d_in[10];
    const float* g3 = (const float*)d_in[12];
    const float* be3= (const float*)d_in[13];
    const float* W4 = (const float*)d_in[14];
    const float* b4 = (const float*)d_in[15];
    float* out = (float*)d_out;

    const int N = in_sizes[0] / 128;
    const int E = in_sizes[1] / 2;
    const int* srcI = ei;
    const int* dstI = ei + E;
    const int NB = cdiv(N, SCHUNK);

    char* p = (char*)d_ws;
    auto carve = [&](size_t bytes) {
        void* q = (void*)p;
        p += (bytes + 255) & ~(size_t)255;
        return q;
    };
    int*   cnt     = (int*)  carve((size_t)N * 4);
    int*   cursor  = (int*)  carve((size_t)N * 4);
    int*   offsets = (int*)  carve((size_t)(N + 1) * 4);
    float* dinv    = (float*)carve((size_t)N * 4);
    int*   csr_src = (int*)  carve((size_t)E * 4);
    int*   bsum    = (int*)  carve((size_t)(NB + 1) * 4);
    float* stats   = (float*)carve(384 * 4);   // L1@0 (2x16), L2@128 (2x32), L3@256 (2x64)
    float* A       = (float*)carve((size_t)N * 64 * 4);
    float* B       = (float*)carve((size_t)N * 64 * 4);

    // --- CSR build ---
    setup_kernel<<<cdiv(N, TPB), TPB, 0, stream>>>(cnt, cursor, stats, N);
    count_kernel<<<cdiv(E, TPB), TPB, 0, stream>>>(dstI, cnt, E);
    scan_reduce_kernel<<<NB, TPB, 0, stream>>>(cnt, bsum, N);
    scan_bsum_kernel<<<1, 64, 0, stream>>>(bsum, offsets, NB, N);
    scan_apply_kernel<<<NB, TPB, 0, stream>>>(cnt, bsum, offsets, dinv, N);
    fill_kernel<<<2048, TPB, 0, stream>>>(srcI, dstI, offsets, cursor, csr_src, E, N);

    // --- L1: transform(128->16, prescaled) then aggregate(16) [stats fused] ---
    gemm_kernel<128, 16, false, true><<<2048, TPB, 0, stream>>>(x, W1, A, nullptr, dinv, N);
    agg4_kernel<16, true><<<1024, TPB, 0, stream>>>(A, B, dinv, offsets, csr_src, stats + 0, N);
    bn_gelu_kernel<16, true><<<cdiv((long long)N * 16, TPB), TPB, 0, stream>>>(B, stats + 0, g1, be1, dinv, N);

    // --- L2: aggregate(16) then transform(16->32) [stats fused into gemm] ---
    agg4_kernel<16, false><<<cdiv((long long)N * 4, TPB), TPB, 0, stream>>>(B, A, dinv, offsets, csr_src, nullptr, N);
    gemm_kernel<16, 32, true, false><<<1024, TPB, 0, stream>>>(A, W2, B, stats + 128, nullptr, N);
    bn_gelu_kernel<32, true><<<cdiv((long long)N * 32, TPB), TPB, 0, stream>>>(B, stats + 128, g2, be2, dinv, N);

    // --- L3: aggregate(32) then transform(32->64) [stats fused into gemm] ---
    agg4_kernel<32, false><<<cdiv((long long)N * 8, TPB), TPB, 0, stream>>>(B, A, dinv, offsets, csr_src, nullptr, N);
    gemm_kernel<32, 64, true, false><<<1024, TPB, 0, stream>>>(A, W3, B, stats + 256, nullptr, N);
    bn_gelu_kernel<64, false><<<cdiv((long long)N * 64, TPB), TPB, 0, stream>>>(B, stats + 256, g3, be3, nullptr, N);

    // --- L4: transform(64->10, prescaled) then aggregate(10)+b4+log_softmax ---
    gemm_kernel<64, 10, false, true><<<1024, TPB, 0, stream>>>(B, W4, A, nullptr, dinv, N);
    agg_lsm_kernel<<<cdiv((long long)N * 16, TPB), TPB, 0, stream>>>(A, dinv, offsets, csr_src, b4, out, N);
}

// Round 7
// 524.206 us; speedup vs baseline: 1.5378x; 1.0544x over previous
//
#include <hip/hip_runtime.h>
#include <math.h>

// GCN: 4x GCNConv (self-loops, sym-norm) + BN+GELU between, log_softmax at end.
// CSR (by dst) built per call; aggregation = atomic-free gather; aggregate on the
// narrow side of each layer (linearity); BN bias-cancellation drops b1..b3.
// R1: hierarchical scan, fused BN-stats, fused log_softmax. 806 -> 622 us.
// R4: dst-windowed fill + dinv-prescale + unrolled gather. 622 -> 553 us.
//     POST-MORTEM: WRITE_SIZE unchanged (102 MB) -> windowing did NOT merge lines;
//     every scattered 4B store costs a 64B writeback (cross-XCD lines never merge).
// R6: bucket-sort CSR build with COALESCED writes only:
//     C1 chunk-histogram(256 dst-buckets) -> scan -> C2 LDS-staged bucket scatter
//     (sequential run writes) -> D per-bucket CSR segment built in LDS, streamed
//     out as full lines. Replaces fill_kernel (78us, 102MB wr) entirely.

#define TPB 256
#define K_BUCK 256
#define CCHUNK 4096   // edges per chunk in C1/C2 (stage = 32 KB LDS)
#define DCAP 8192     // per-bucket CSR LDS capacity (32 KB); mean 6250, +24 sigma
constexpr float BN_EPS = 1e-5f;

// ---------------- small utils ----------------

__global__ void setup_kernel(int* __restrict__ cnt, float* __restrict__ stats, int n) {
    int i = blockIdx.x * blockDim.x + threadIdx.x;
    if (i < n) cnt[i] = 0;
    if (i < 384) stats[i] = 0.0f;
}

__global__ void count_kernel(const int* __restrict__ dst, int* __restrict__ cnt, int e) {
    int i = blockIdx.x * blockDim.x + threadIdx.x;
    if (i < e) atomicAdd(&cnt[dst[i]], 1);
}

#define SCHUNK 2048  // elements per scan block (256 thr x 8)

__global__ void scan_reduce_kernel(const int* __restrict__ in, int* __restrict__ bsum, int n) {
    int base = blockIdx.x * SCHUNK;
    int s = 0;
    for (int j = threadIdx.x; j < SCHUNK; j += TPB) {
        int i = base + j;
        s += (i < n) ? in[i] : 0;
    }
#pragma unroll
    for (int d = 32; d; d >>= 1) s += __shfl_down(s, d);
    __shared__ int ws[TPB / 64];
    if ((threadIdx.x & 63) == 0) ws[threadIdx.x >> 6] = s;
    __syncthreads();
    if (threadIdx.x == 0) {
        int t = 0;
        for (int w = 0; w < TPB / 64; ++w) t += ws[w];
        bsum[blockIdx.x] = t;
    }
}

// single wave: exclusive-scan bsum[0..nb); optional grand total to *total_out
__global__ void scan_bsum_kernel(int* __restrict__ bsum, int* __restrict__ total_out, int nb) {
    __shared__ int carry;
    int lane = threadIdx.x;
    if (lane == 0) carry = 0;
    __syncthreads();
    for (int base = 0; base < nb; base += 64) {
        int i = base + lane;
        int v = (i < nb) ? bsum[i] : 0;
        int incl = v;
#pragma unroll
        for (int d = 1; d < 64; d <<= 1) {
            int u = __shfl_up(incl, d);
            if (lane >= d) incl += u;
        }
        if (i < nb) bsum[i] = carry + incl - v;
        int tot = __shfl(incl, 63);
        __syncthreads();
        if (lane == 0) carry += tot;
        __syncthreads();
    }
    if (lane == 0 && total_out) *total_out = carry;
}

// block-local scan + apply block prefix; optionally also computes dinv from counts
template <bool DINV>
__global__ void scan_apply_kernel(const int* __restrict__ in, const int* __restrict__ bsum,
                                  int* __restrict__ out, float* __restrict__ dinv, int n) {
    int base = blockIdx.x * SCHUNK;
    int tid = threadIdx.x;
    int lane = tid & 63, wave = tid >> 6;
    int i0 = base + tid * 8;
    int v[8];
    int tsum = 0;
#pragma unroll
    for (int k = 0; k < 8; ++k) {
        int i = i0 + k;
        v[k] = (i < n) ? in[i] : 0;
        tsum += v[k];
    }
    int incl = tsum;
#pragma unroll
    for (int d = 1; d < 64; d <<= 1) {
        int u = __shfl_up(incl, d);
        if (lane >= d) incl += u;
    }
    int lexcl = incl - tsum;
    __shared__ int wsum[TPB / 64];
    if (lane == 63) wsum[wave] = incl;
    __syncthreads();
    int wbase = 0;
    for (int w = 0; w < wave; ++w) wbase += wsum[w];
    int off = bsum[blockIdx.x] + wbase + lexcl;
#pragma unroll
    for (int k = 0; k < 8; ++k) {
        int i = i0 + k;
        if (i < n) {
            out[i] = off;
            if (DINV) dinv[i] = rsqrtf((float)(v[k] + 1));  // +1 = self loop
        }
        off += v[k];
    }
}

// ---------------- bucket-sort CSR build (all writes coalesced) ----------------

// C1: per-chunk histogram over K_BUCK dst-buckets -> hist[bucket * nb + chunk]
__global__ void bucket_hist_kernel(const int* __restrict__ dst, int* __restrict__ hist,
                                   int e, int n, int nb) {
    __shared__ int lh[K_BUCK];
    for (int i = threadIdx.x; i < K_BUCK; i += TPB) lh[i] = 0;
    __syncthreads();
    int base = blockIdx.x * CCHUNK;
    int end = min(base + CCHUNK, e);
    int div = (n + K_BUCK - 1) / K_BUCK;
    for (int i = base + threadIdx.x; i < end; i += TPB) atomicAdd(&lh[dst[i] / div], 1);
    __syncthreads();
    for (int b = threadIdx.x; b < K_BUCK; b += TPB) hist[b * nb + blockIdx.x] = lh[b];
}

// C2: re-read chunk, group edges by bucket in LDS, flush runs to ebuf with
// sequential (coalesced) writes. hbase = exclusive scan of hist (bucket-major).
__global__ void bucket_scatter_kernel(const int* __restrict__ src, const int* __restrict__ dst,
                                      const int* __restrict__ hist, const int* __restrict__ hbase,
                                      int2* __restrict__ ebuf, int e, int n, int nb) {
    __shared__ int lbase[K_BUCK];  // global base of this (chunk,bucket) run
    __shared__ int eoff[K_BUCK];   // exclusive local offset of bucket in stage
    __shared__ int lcur[K_BUCK];   // local cursor
    __shared__ int2 stage[CCHUNK];
    int t = threadIdx.x;  // TPB == K_BUCK
    int blk = blockIdx.x;
    int c = hist[t * nb + blk];
    lbase[t] = hbase[t * nb + blk];
    lcur[t] = 0;
    eoff[t] = c;
    __syncthreads();
    for (int d = 1; d < K_BUCK; d <<= 1) {  // inclusive scan of counts
        int v = (t >= d) ? eoff[t - d] : 0;
        __syncthreads();
        eoff[t] += v;
        __syncthreads();
    }
    eoff[t] -= c;  // exclusive
    __syncthreads();
    int base = blk * CCHUNK;
    int end = min(base + CCHUNK, e);
    int div = (n + K_BUCK - 1) / K_BUCK;
    for (int i = base + t; i < end; i += TPB) {
        int d = dst[i];
        int b = d / div;
        int p = atomicAdd(&lcur[b], 1);
        stage[eoff[b] + p] = make_int2(src[i], d);
    }
    __syncthreads();
    int cnt_here = end - base;
    for (int j = t; j < cnt_here; j += TPB) {
        int2 e2 = stage[j];
        int b = e2.y / div;
        ebuf[lbase[b] + (j - eoff[b])] = e2;  // coalesced within runs
    }
}

// D: one block per bucket; build the bucket's CSR segment in LDS via local
// cursors (offsets - segbase), then stream it out as full coalesced lines.
__global__ void csr_fill_kernel(const int2* __restrict__ ebuf, const int* __restrict__ hbase,
                                const int* __restrict__ offsets, int* __restrict__ csr_src,
                                int e, int n, int nb) {
    __shared__ int lcur[400];
    __shared__ int lcsr[DCAP];
    int b = blockIdx.x;
    int div = (n + K_BUCK - 1) / K_BUCK;
    int lo = b * div;
    int hi = min(lo + div, n);
    int ebeg = hbase[b * nb];
    int eend = (b == K_BUCK - 1) ? e : hbase[(b + 1) * nb];
    int segbase = offsets[lo];
    int seglen = eend - ebeg;
    for (int i = threadIdx.x; i < hi - lo; i += TPB) lcur[i] = offsets[lo + i] - segbase;
    __syncthreads();
    for (int j = ebeg + threadIdx.x; j < eend; j += TPB) {
        int2 e2 = ebuf[j];
        int p = atomicAdd(&lcur[e2.y - lo], 1);
        if (p < DCAP) lcsr[p] = e2.x;
        else csr_src[segbase + p] = e2.x;  // overflow guard (statistically never)
    }
    __syncthreads();
    int lim = min(seglen, DCAP);
    for (int j = threadIdx.x; j < lim; j += TPB) csr_src[segbase + j] = lcsr[j];
}

// ---------------- dense transforms ----------------

// Grid-stride H[n,FIN] @ W[FIN,FOUT] -> O[n,FOUT]; optional fused BN-stats
// (on unscaled output) and optional output prescale by dinv[row] (for next agg).
// col per thread is loop-invariant because stride % FOUT == 0.
template <int FIN, int FOUT, bool STATS, bool DINV>
__global__ void gemm_kernel(const float* __restrict__ H, const float* __restrict__ W,
                            float* __restrict__ O, float* __restrict__ stats,
                            const float* __restrict__ dinv, int n) {
    __shared__ float Ws[FIN * FOUT];
    __shared__ float sh[STATS ? 2 * FOUT : 1];
    for (int i = threadIdx.x; i < FIN * FOUT; i += blockDim.x) Ws[i] = W[i];
    if (STATS)
        for (int i = threadIdx.x; i < 2 * FOUT; i += blockDim.x) sh[i] = 0.0f;
    __syncthreads();
    long long total = (long long)n * FOUT;
    long long stride = (long long)gridDim.x * blockDim.x;
    float s = 0.0f, s2 = 0.0f;
    int col0 = -1;
    for (long long gid = (long long)blockIdx.x * blockDim.x + threadIdx.x; gid < total;
         gid += stride) {
        int row = (int)(gid / FOUT);
        int col = (int)(gid % FOUT);
        const float* h = H + (size_t)row * FIN;
        float acc = 0.0f;
#pragma unroll
        for (int k = 0; k < FIN; ++k) acc = fmaf(h[k], Ws[k * FOUT + col], acc);
        if (STATS) { s += acc; s2 = fmaf(acc, acc, s2); col0 = col; }
        O[gid] = DINV ? acc * dinv[row] : acc;
    }
    if (STATS) {
        if (col0 >= 0) {
            atomicAdd(&sh[col0], s);
            atomicAdd(&sh[FOUT + col0], s2);
        }
        __syncthreads();
        for (int i = threadIdx.x; i < 2 * FOUT; i += blockDim.x) atomicAdd(&stats[i], sh[i]);
    }
}

// ---------------- aggregation ----------------

// Gather-aggregate over dinv-PRESCALED table T' (T'[u] = T[u]*dinv[u]):
//   out[node] = dinv[node] * (sum_{u in nbr} T'[u] + T'[node])
// Inner loop is pure gather+add, unrolled x4 for MLP. F%4==0: F/4 lanes/node.
template <int F, bool STATS>
__global__ void agg4_kernel(const float* __restrict__ T, float* __restrict__ A,
                            const float* __restrict__ dinv, const int* __restrict__ offsets,
                            const int* __restrict__ csr_src, float* __restrict__ stats, int n) {
    constexpr int G = F / 4;
    __shared__ float sh[STATS ? 2 * F : 1];
    if (STATS) {
        for (int i = threadIdx.x; i < 2 * F; i += blockDim.x) sh[i] = 0.0f;
        __syncthreads();
    }
    const float4* T4 = (const float4*)T;
    float4 ss = {0, 0, 0, 0}, s2 = {0, 0, 0, 0};
    int lane0 = -1;
    int total = n * G;
    int stride = gridDim.x * blockDim.x;  // % G == 0 since TPB % G == 0
    for (int idx = blockIdx.x * blockDim.x + threadIdx.x; idx < total; idx += stride) {
        int node = idx / G;
        int lane = idx % G;
        float4 acc = T4[(size_t)node * G + lane];  // self term (prescaled)
        int s = offsets[node], e = offsets[node + 1];
        int j = s;
        for (; j + 3 < e; j += 4) {
            int u0 = csr_src[j], u1 = csr_src[j + 1], u2 = csr_src[j + 2], u3 = csr_src[j + 3];
            float4 t0 = T4[(size_t)u0 * G + lane];
            float4 t1 = T4[(size_t)u1 * G + lane];
            float4 t2 = T4[(size_t)u2 * G + lane];
            float4 t3 = T4[(size_t)u3 * G + lane];
            acc.x += (t0.x + t1.x) + (t2.x + t3.x);
            acc.y += (t0.y + t1.y) + (t2.y + t3.y);
            acc.z += (t0.z + t1.z) + (t2.z + t3.z);
            acc.w += (t0.w + t1.w) + (t2.w + t3.w);
        }
        for (; j < e; ++j) {
            int u = csr_src[j];
            float4 t = T4[(size_t)u * G + lane];
            acc.x += t.x; acc.y += t.y; acc.z += t.z; acc.w += t.w;
        }
        float di = dinv[node];
        acc.x *= di; acc.y *= di; acc.z *= di; acc.w *= di;
        ((float4*)A)[(size_t)idx] = acc;
        if (STATS) {
            ss.x += acc.x; ss.y += acc.y; ss.z += acc.z; ss.w += acc.w;
            s2.x = fmaf(acc.x, acc.x, s2.x); s2.y = fmaf(acc.y, acc.y, s2.y);
            s2.z = fmaf(acc.z, acc.z, s2.z); s2.w = fmaf(acc.w, acc.w, s2.w);
            lane0 = lane;
        }
    }
    if (STATS) {
        if (lane0 >= 0) {
            atomicAdd(&sh[lane0 * 4 + 0], ss.x); atomicAdd(&sh[lane0 * 4 + 1], ss.y);
            atomicAdd(&sh[lane0 * 4 + 2], ss.z); atomicAdd(&sh[lane0 * 4 + 3], ss.w);
            atomicAdd(&sh[F + lane0 * 4 + 0], s2.x); atomicAdd(&sh[F + lane0 * 4 + 1], s2.y);
            atomicAdd(&sh[F + lane0 * 4 + 2], s2.z); atomicAdd(&sh[F + lane0 * 4 + 3], s2.w);
        }
        __syncthreads();
        for (int i = threadIdx.x; i < 2 * F; i += blockDim.x) atomicAdd(&stats[i], sh[i]);
    }
}

// Final layer: aggregate prescaled F=10 (16 lanes/node) + b4 + log_softmax.
__global__ void agg_lsm_kernel(const float* __restrict__ T, const float* __restrict__ dinv,
                               const int* __restrict__ offsets, const int* __restrict__ csr_src,
                               const float* __restrict__ b4, float* __restrict__ out, int n) {
    int idx = blockIdx.x * blockDim.x + threadIdx.x;
    int node = idx >> 4;
    int lane = idx & 15;
    if (node >= n) return;
    bool act = lane < 10;
    float acc = act ? T[(size_t)node * 10 + lane] : 0.0f;  // self (prescaled)
    int s = offsets[node], e = offsets[node + 1];
    int j = s;
    for (; j + 1 < e; j += 2) {
        int u0 = csr_src[j], u1 = csr_src[j + 1];
        float t0 = act ? T[(size_t)u0 * 10 + lane] : 0.0f;
        float t1 = act ? T[(size_t)u1 * 10 + lane] : 0.0f;
        acc += t0 + t1;
    }
    if (j < e) {
        int u = csr_src[j];
        if (act) acc += T[(size_t)u * 10 + lane];
    }
    float v = act ? fmaf(dinv[node], acc, b4[lane]) : -1e30f;
    float m = v;
#pragma unroll
    for (int d = 1; d < 16; d <<= 1) m = fmaxf(m, __shfl_xor(m, d));
    float ex = act ? expf(v - m) : 0.0f;
    float sum = ex;
#pragma unroll
    for (int d = 1; d < 16; d <<= 1) sum += __shfl_xor(sum, d);
    if (act) out[(size_t)node * 10 + lane] = v - m - logf(sum);
}

// ---------------- BN + GELU ----------------

// In-place BN (batch stats) + exact GELU; optional prescale by dinv (next-agg fusion).
template <int F, bool DINV>
__global__ void bn_gelu_kernel(float* __restrict__ V, const float* __restrict__ stats,
                               const float* __restrict__ g, const float* __restrict__ be,
                               const float* __restrict__ dinv, int n) {
    int i = blockIdx.x * blockDim.x + threadIdx.x;
    if (i >= n * F) return;
    int f = i % F;
    float inv_n = 1.0f / (float)n;
    float mu = stats[f] * inv_n;
    float var = stats[F + f] * inv_n - mu * mu;
    float sc = rsqrtf(var + BN_EPS) * g[f];
    float shf = be[f] - mu * sc;
    float x = fmaf(V[i], sc, shf);
    float y = 0.5f * x * (1.0f + erff(x * 0.70710678118654752f));
    V[i] = DINV ? y * dinv[i / F] : y;
}

static inline int cdiv(long long a, int b) { return (int)((a + b - 1) / b); }

extern "C" void kernel_launch(void* const* d_in, const int* in_sizes, int n_in,
                              void* d_out, int out_size, void* d_ws, size_t ws_size,
                              hipStream_t stream) {
    const float* x  = (const float*)d_in[0];
    const int*   ei = (const int*)d_in[1];
    const float* W1 = (const float*)d_in[2];
    const float* g1 = (const float*)d_in[4];
    const float* be1= (const float*)d_in[5];
    const float* W2 = (const float*)d_in[6];
    const float* g2 = (const float*)d_in[8];
    const float* be2= (const float*)d_in[9];
    const float* W3 = (const float*)d_in[10];
    const float* g3 = (const float*)d_in[12];
    const float* be3= (const float*)d_in[13];
    const float* W4 = (const float*)d_in[14];
    const float* b4 = (const float*)d_in[15];
    float* out = (float*)d_out;

    const int N = in_sizes[0] / 128;
    const int E = in_sizes[1] / 2;
    const int* srcI = ei;
    const int* dstI = ei + E;
    const int NBn = cdiv(N, SCHUNK);           // scan blocks for offsets
    const int NBc = cdiv(E, CCHUNK);           // edge chunks
    const int HN  = K_BUCK * NBc;              // histogram entries
    const int NBh = cdiv(HN, SCHUNK);          // scan blocks for hist

    char* p = (char*)d_ws;
    auto carve = [&](size_t bytes) {
        void* q = (void*)p;
        p += (bytes + 255) & ~(size_t)255;
        return q;
    };
    int*   cnt     = (int*)  carve((size_t)N * 4);
    int*   offsets = (int*)  carve((size_t)(N + 1) * 4);
    float* dinv    = (float*)carve((size_t)N * 4);
    int*   csr_src = (int*)  carve((size_t)E * 4);
    int*   hist    = (int*)  carve((size_t)HN * 4);
    int*   hbase   = (int*)  carve((size_t)(HN + 1) * 4);
    int2*  ebuf    = (int2*) carve((size_t)E * 8);
    int*   bsum    = (int*)  carve((size_t)(((NBn > NBh) ? NBn : NBh) + 1) * 4);
    float* stats   = (float*)carve(384 * 4);   // L1@0 (2x16), L2@128 (2x32), L3@256 (2x64)
    float* A       = (float*)carve((size_t)N * 64 * 4);
    float* B       = (float*)carve((size_t)N * 64 * 4);

    // --- degree + offsets + dinv ---
    setup_kernel<<<cdiv(N, TPB), TPB, 0, stream>>>(cnt, stats, N);
    count_kernel<<<cdiv(E, TPB), TPB, 0, stream>>>(dstI, cnt, E);
    scan_reduce_kernel<<<NBn, TPB, 0, stream>>>(cnt, bsum, N);
    scan_bsum_kernel<<<1, 64, 0, stream>>>(bsum, offsets + N, NBn);
    scan_apply_kernel<true><<<NBn, TPB, 0, stream>>>(cnt, bsum, offsets, dinv, N);

    // --- bucket-sort CSR build (coalesced writes) ---
    bucket_hist_kernel<<<NBc, TPB, 0, stream>>>(dstI, hist, E, N, NBc);
    scan_reduce_kernel<<<NBh, TPB, 0, stream>>>(hist, bsum, HN);
    scan_bsum_kernel<<<1, 64, 0, stream>>>(bsum, hbase + HN, NBh);
    scan_apply_kernel<false><<<NBh, TPB, 0, stream>>>(hist, bsum, hbase, nullptr, HN);
    bucket_scatter_kernel<<<NBc, TPB, 0, stream>>>(srcI, dstI, hist, hbase, ebuf, E, N, NBc);
    csr_fill_kernel<<<K_BUCK, TPB, 0, stream>>>(ebuf, hbase, offsets, csr_src, E, N, NBc);

    // --- L1: transform(128->16, prescaled) then aggregate(16) [stats fused] ---
    gemm_kernel<128, 16, false, true><<<2048, TPB, 0, stream>>>(x, W1, A, nullptr, dinv, N);
    agg4_kernel<16, true><<<1024, TPB, 0, stream>>>(A, B, dinv, offsets, csr_src, stats + 0, N);
    bn_gelu_kernel<16, true><<<cdiv((long long)N * 16, TPB), TPB, 0, stream>>>(B, stats + 0, g1, be1, dinv, N);

    // --- L2: aggregate(16) then transform(16->32) [stats fused into gemm] ---
    agg4_kernel<16, false><<<cdiv((long long)N * 4, TPB), TPB, 0, stream>>>(B, A, dinv, offsets, csr_src, nullptr, N);
    gemm_kernel<16, 32, true, false><<<1024, TPB, 0, stream>>>(A, W2, B, stats + 128, nullptr, N);
    bn_gelu_kernel<32, true><<<cdiv((long long)N * 32, TPB), TPB, 0, stream>>>(B, stats + 128, g2, be2, dinv, N);

    // --- L3: aggregate(32) then transform(32->64) [stats fused into gemm] ---
    agg4_kernel<32, false><<<cdiv((long long)N * 8, TPB), TPB, 0, stream>>>(B, A, dinv, offsets, csr_src, nullptr, N);
    gemm_kernel<32, 64, true, false><<<1024, TPB, 0, stream>>>(A, W3, B, stats + 256, nullptr, N);
    bn_gelu_kernel<64, false><<<cdiv((long long)N * 64, TPB), TPB, 0, stream>>>(B, stats + 256, g3, be3, nullptr, N);

    // --- L4: transform(64->10, prescaled) then aggregate(10)+b4+log_softmax ---
    gemm_kernel<64, 10, false, true><<<1024, TPB, 0, stream>>>(B, W4, A, nullptr, dinv, N);
    agg_lsm_kernel<<<cdiv((long long)N * 16, TPB), TPB, 0, stream>>>(A, dinv, offsets, csr_src, b4, out, N);
}

// Round 9
// 450.172 us; speedup vs baseline: 1.7907x; 1.1645x over previous
//
#include <hip/hip_runtime.h>
#include <math.h>

// GCN: 4x GCNConv (self-loops, sym-norm) + BN+GELU between, log_softmax at end.
// CSR (by dst) built per call; aggregation = atomic-free gather; aggregate on the
// narrow side of each layer (linearity); BN bias-cancellation drops b1..b3.
// R1: hierarchical scan, fused BN-stats, fused log_softmax. 806 -> 622 us.
// R4: dinv-prescale + unrolled gather. 622 -> 553 us. (dst-windowing: no effect on WR)
// R6: bucket-sort CSR build, all writes coalesced. 553 -> 524 us.
// R7: count_kernel (65us, 50MB scattered-atomic writebacks) DELETED — degrees,
//     offsets and dinv are derived per-bucket from the bucket-sorted ebuf using
//     LDS atomics + wave scan (segbase = hbase[b*nb] gives the global prefix free).
//     Also deletes the 3 N-sized scan kernels; stats-zeroing folded into bucket_hist.
// R8: resubmit of R7 (broker timeout, no measurement).

#define TPB 256
#define K_BUCK 256
#define CCHUNK 4096   // edges per chunk in C1/C2 (stage = 32 KB LDS)
#define DCAP 8192     // per-bucket CSR LDS capacity (32 KB); mean 6250, +24 sigma
constexpr float BN_EPS = 1e-5f;

#define SCHUNK 2048  // elements per scan block (256 thr x 8)

__global__ void scan_reduce_kernel(const int* __restrict__ in, int* __restrict__ bsum, int n) {
    int base = blockIdx.x * SCHUNK;
    int s = 0;
    for (int j = threadIdx.x; j < SCHUNK; j += TPB) {
        int i = base + j;
        s += (i < n) ? in[i] : 0;
    }
#pragma unroll
    for (int d = 32; d; d >>= 1) s += __shfl_down(s, d);
    __shared__ int ws[TPB / 64];
    if ((threadIdx.x & 63) == 0) ws[threadIdx.x >> 6] = s;
    __syncthreads();
    if (threadIdx.x == 0) {
        int t = 0;
        for (int w = 0; w < TPB / 64; ++w) t += ws[w];
        bsum[blockIdx.x] = t;
    }
}

// single wave: exclusive-scan bsum[0..nb)
__global__ void scan_bsum_kernel(int* __restrict__ bsum, int nb) {
    __shared__ int carry;
    int lane = threadIdx.x;
    if (lane == 0) carry = 0;
    __syncthreads();
    for (int base = 0; base < nb; base += 64) {
        int i = base + lane;
        int v = (i < nb) ? bsum[i] : 0;
        int incl = v;
#pragma unroll
        for (int d = 1; d < 64; d <<= 1) {
            int u = __shfl_up(incl, d);
            if (lane >= d) incl += u;
        }
        if (i < nb) bsum[i] = carry + incl - v;
        int tot = __shfl(incl, 63);
        __syncthreads();
        if (lane == 0) carry += tot;
        __syncthreads();
    }
}

// block-local scan + apply block prefix
__global__ void scan_apply_kernel(const int* __restrict__ in, const int* __restrict__ bsum,
                                  int* __restrict__ out, int n) {
    int base = blockIdx.x * SCHUNK;
    int tid = threadIdx.x;
    int lane = tid & 63, wave = tid >> 6;
    int i0 = base + tid * 8;
    int v[8];
    int tsum = 0;
#pragma unroll
    for (int k = 0; k < 8; ++k) {
        int i = i0 + k;
        v[k] = (i < n) ? in[i] : 0;
        tsum += v[k];
    }
    int incl = tsum;
#pragma unroll
    for (int d = 1; d < 64; d <<= 1) {
        int u = __shfl_up(incl, d);
        if (lane >= d) incl += u;
    }
    int lexcl = incl - tsum;
    __shared__ int wsum[TPB / 64];
    if (lane == 63) wsum[wave] = incl;
    __syncthreads();
    int wbase = 0;
    for (int w = 0; w < wave; ++w) wbase += wsum[w];
    int off = bsum[blockIdx.x] + wbase + lexcl;
#pragma unroll
    for (int k = 0; k < 8; ++k) {
        int i = i0 + k;
        if (i < n) out[i] = off;
        off += v[k];
    }
}

// ---------------- bucket-sort CSR build (all writes coalesced) ----------------

// C1: per-chunk histogram over K_BUCK dst-buckets -> hist[bucket * nb + chunk].
// Block 0 also zeroes the BN stats accumulators (runs well before any stats use).
__global__ void bucket_hist_kernel(const int* __restrict__ dst, int* __restrict__ hist,
                                   float* __restrict__ stats, int e, int n, int nb) {
    __shared__ int lh[K_BUCK];
    for (int i = threadIdx.x; i < K_BUCK; i += TPB) lh[i] = 0;
    if (blockIdx.x == 0)
        for (int i = threadIdx.x; i < 384; i += TPB) stats[i] = 0.0f;
    __syncthreads();
    int base = blockIdx.x * CCHUNK;
    int end = min(base + CCHUNK, e);
    int div = (n + K_BUCK - 1) / K_BUCK;
    for (int i = base + threadIdx.x; i < end; i += TPB) atomicAdd(&lh[dst[i] / div], 1);
    __syncthreads();
    for (int b = threadIdx.x; b < K_BUCK; b += TPB) hist[b * nb + blockIdx.x] = lh[b];
}

// C2: re-read chunk, group edges by bucket in LDS, flush runs to ebuf with
// sequential (coalesced) writes. hbase = exclusive scan of hist (bucket-major).
__global__ void bucket_scatter_kernel(const int* __restrict__ src, const int* __restrict__ dst,
                                      const int* __restrict__ hist, const int* __restrict__ hbase,
                                      int2* __restrict__ ebuf, int e, int n, int nb) {
    __shared__ int lbase[K_BUCK];  // global base of this (chunk,bucket) run
    __shared__ int eoff[K_BUCK];   // exclusive local offset of bucket in stage
    __shared__ int lcur[K_BUCK];   // local cursor
    __shared__ int2 stage[CCHUNK];
    int t = threadIdx.x;  // TPB == K_BUCK
    int blk = blockIdx.x;
    int c = hist[t * nb + blk];
    lbase[t] = hbase[t * nb + blk];
    lcur[t] = 0;
    eoff[t] = c;
    __syncthreads();
    for (int d = 1; d < K_BUCK; d <<= 1) {  // inclusive scan of counts
        int v = (t >= d) ? eoff[t - d] : 0;
        __syncthreads();
        eoff[t] += v;
        __syncthreads();
    }
    eoff[t] -= c;  // exclusive
    __syncthreads();
    int base = blk * CCHUNK;
    int end = min(base + CCHUNK, e);
    int div = (n + K_BUCK - 1) / K_BUCK;
    for (int i = base + t; i < end; i += TPB) {
        int d = dst[i];
        int b = d / div;
        int p = atomicAdd(&lcur[b], 1);
        stage[eoff[b] + p] = make_int2(src[i], d);
    }
    __syncthreads();
    int cnt_here = end - base;
    for (int j = t; j < cnt_here; j += TPB) {
        int2 e2 = stage[j];
        int b = e2.y / div;
        ebuf[lbase[b] + (j - eoff[b])] = e2;  // coalesced within runs
    }
}

// R7: per-bucket degree count (LDS atomics) + local wave scan -> offsets,
// dinv written coalesced. Global prefix at bucket boundary = hbase[b*nb] (free).
__global__ void bucket_offsets_kernel(const int2* __restrict__ ebuf, const int* __restrict__ hbase,
                                      int* __restrict__ offsets, float* __restrict__ dinv,
                                      int e, int n, int nb) {
    __shared__ int lcnt[512];
    __shared__ int lexc[512];
    int b = blockIdx.x;
    int div = (n + K_BUCK - 1) / K_BUCK;
    int lo = b * div;
    int hi = min(lo + div, n);
    int nloc = hi - lo;
    int ebeg = hbase[b * nb];
    int eend = (b == K_BUCK - 1) ? e : hbase[(b + 1) * nb];
    for (int i = threadIdx.x; i < 512; i += TPB) lcnt[i] = 0;
    __syncthreads();
    for (int j = ebeg + threadIdx.x; j < eend; j += TPB)
        atomicAdd(&lcnt[ebuf[j].y - lo], 1);
    __syncthreads();
    if (threadIdx.x < 64) {  // wave 0: exclusive scan of lcnt[0..512)
        int l = threadIdx.x;
        int base = l * 8;
        int v[8];
        int tsum = 0;
#pragma unroll
        for (int k = 0; k < 8; ++k) { v[k] = lcnt[base + k]; tsum += v[k]; }
        int incl = tsum;
#pragma unroll
        for (int d = 1; d < 64; d <<= 1) {
            int u = __shfl_up(incl, d);
            if (l >= d) incl += u;
        }
        int off = incl - tsum;
#pragma unroll
        for (int k = 0; k < 8; ++k) { lexc[base + k] = off; off += v[k]; }
    }
    __syncthreads();
    for (int i = threadIdx.x; i < nloc; i += TPB) {
        offsets[lo + i] = ebeg + lexc[i];
        dinv[lo + i] = rsqrtf((float)(lcnt[i] + 1));  // +1 = self loop
    }
    if (b == K_BUCK - 1 && threadIdx.x == 0) offsets[n] = e;
}

// D: one block per bucket; build the bucket's CSR segment in LDS via local
// cursors (offsets - segbase), then stream it out as full coalesced lines.
__global__ void csr_fill_kernel(const int2* __restrict__ ebuf, const int* __restrict__ hbase,
                                const int* __restrict__ offsets, int* __restrict__ csr_src,
                                int e, int n, int nb) {
    __shared__ int lcur[400];
    __shared__ int lcsr[DCAP];
    int b = blockIdx.x;
    int div = (n + K_BUCK - 1) / K_BUCK;
    int lo = b * div;
    int hi = min(lo + div, n);
    int ebeg = hbase[b * nb];
    int eend = (b == K_BUCK - 1) ? e : hbase[(b + 1) * nb];
    int segbase = offsets[lo];
    int seglen = eend - ebeg;
    for (int i = threadIdx.x; i < hi - lo; i += TPB) lcur[i] = offsets[lo + i] - segbase;
    __syncthreads();
    for (int j = ebeg + threadIdx.x; j < eend; j += TPB) {
        int2 e2 = ebuf[j];
        int p = atomicAdd(&lcur[e2.y - lo], 1);
        if (p < DCAP) lcsr[p] = e2.x;
        else csr_src[segbase + p] = e2.x;  // overflow guard (statistically never)
    }
    __syncthreads();
    int lim = min(seglen, DCAP);
    for (int j = threadIdx.x; j < lim; j += TPB) csr_src[segbase + j] = lcsr[j];
}

// ---------------- dense transforms ----------------

// Grid-stride H[n,FIN] @ W[FIN,FOUT] -> O[n,FOUT]; optional fused BN-stats
// (on unscaled output) and optional output prescale by dinv[row] (for next agg).
// col per thread is loop-invariant because stride % FOUT == 0.
template <int FIN, int FOUT, bool STATS, bool DINV>
__global__ void gemm_kernel(const float* __restrict__ H, const float* __restrict__ W,
                            float* __restrict__ O, float* __restrict__ stats,
                            const float* __restrict__ dinv, int n) {
    __shared__ float Ws[FIN * FOUT];
    __shared__ float sh[STATS ? 2 * FOUT : 1];
    for (int i = threadIdx.x; i < FIN * FOUT; i += blockDim.x) Ws[i] = W[i];
    if (STATS)
        for (int i = threadIdx.x; i < 2 * FOUT; i += blockDim.x) sh[i] = 0.0f;
    __syncthreads();
    long long total = (long long)n * FOUT;
    long long stride = (long long)gridDim.x * blockDim.x;
    float s = 0.0f, s2 = 0.0f;
    int col0 = -1;
    for (long long gid = (long long)blockIdx.x * blockDim.x + threadIdx.x; gid < total;
         gid += stride) {
        int row = (int)(gid / FOUT);
        int col = (int)(gid % FOUT);
        const float* h = H + (size_t)row * FIN;
        float acc = 0.0f;
#pragma unroll
        for (int k = 0; k < FIN; ++k) acc = fmaf(h[k], Ws[k * FOUT + col], acc);
        if (STATS) { s += acc; s2 = fmaf(acc, acc, s2); col0 = col; }
        O[gid] = DINV ? acc * dinv[row] : acc;
    }
    if (STATS) {
        if (col0 >= 0) {
            atomicAdd(&sh[col0], s);
            atomicAdd(&sh[FOUT + col0], s2);
        }
        __syncthreads();
        for (int i = threadIdx.x; i < 2 * FOUT; i += blockDim.x) atomicAdd(&stats[i], sh[i]);
    }
}

// ---------------- aggregation ----------------

// Gather-aggregate over dinv-PRESCALED table T' (T'[u] = T[u]*dinv[u]):
//   out[node] = dinv[node] * (sum_{u in nbr} T'[u] + T'[node])
// Inner loop is pure gather+add, unrolled x4 for MLP. F%4==0: F/4 lanes/node.
template <int F, bool STATS>
__global__ void agg4_kernel(const float* __restrict__ T, float* __restrict__ A,
                            const float* __restrict__ dinv, const int* __restrict__ offsets,
                            const int* __restrict__ csr_src, float* __restrict__ stats, int n) {
    constexpr int G = F / 4;
    __shared__ float sh[STATS ? 2 * F : 1];
    if (STATS) {
        for (int i = threadIdx.x; i < 2 * F; i += blockDim.x) sh[i] = 0.0f;
        __syncthreads();
    }
    const float4* T4 = (const float4*)T;
    float4 ss = {0, 0, 0, 0}, s2 = {0, 0, 0, 0};
    int lane0 = -1;
    int total = n * G;
    int stride = gridDim.x * blockDim.x;  // % G == 0 since TPB % G == 0
    for (int idx = blockIdx.x * blockDim.x + threadIdx.x; idx < total; idx += stride) {
        int node = idx / G;
        int lane = idx % G;
        float4 acc = T4[(size_t)node * G + lane];  // self term (prescaled)
        int s = offsets[node], e = offsets[node + 1];
        int j = s;
        for (; j + 3 < e; j += 4) {
            int u0 = csr_src[j], u1 = csr_src[j + 1], u2 = csr_src[j + 2], u3 = csr_src[j + 3];
            float4 t0 = T4[(size_t)u0 * G + lane];
            float4 t1 = T4[(size_t)u1 * G + lane];
            float4 t2 = T4[(size_t)u2 * G + lane];
            float4 t3 = T4[(size_t)u3 * G + lane];
            acc.x += (t0.x + t1.x) + (t2.x + t3.x);
            acc.y += (t0.y + t1.y) + (t2.y + t3.y);
            acc.z += (t0.z + t1.z) + (t2.z + t3.z);
            acc.w += (t0.w + t1.w) + (t2.w + t3.w);
        }
        for (; j < e; ++j) {
            int u = csr_src[j];
            float4 t = T4[(size_t)u * G + lane];
            acc.x += t.x; acc.y += t.y; acc.z += t.z; acc.w += t.w;
        }
        float di = dinv[node];
        acc.x *= di; acc.y *= di; acc.z *= di; acc.w *= di;
        ((float4*)A)[(size_t)idx] = acc;
        if (STATS) {
            ss.x += acc.x; ss.y += acc.y; ss.z += acc.z; ss.w += acc.w;
            s2.x = fmaf(acc.x, acc.x, s2.x); s2.y = fmaf(acc.y, acc.y, s2.y);
            s2.z = fmaf(acc.z, acc.z, s2.z); s2.w = fmaf(acc.w, acc.w, s2.w);
            lane0 = lane;
        }
    }
    if (STATS) {
        if (lane0 >= 0) {
            atomicAdd(&sh[lane0 * 4 + 0], ss.x); atomicAdd(&sh[lane0 * 4 + 1], ss.y);
            atomicAdd(&sh[lane0 * 4 + 2], ss.z); atomicAdd(&sh[lane0 * 4 + 3], ss.w);
            atomicAdd(&sh[F + lane0 * 4 + 0], s2.x); atomicAdd(&sh[F + lane0 * 4 + 1], s2.y);
            atomicAdd(&sh[F + lane0 * 4 + 2], s2.z); atomicAdd(&sh[F + lane0 * 4 + 3], s2.w);
        }
        __syncthreads();
        for (int i = threadIdx.x; i < 2 * F; i += blockDim.x) atomicAdd(&stats[i], sh[i]);
    }
}

// Final layer: aggregate prescaled F=10 (16 lanes/node) + b4 + log_softmax.
__global__ void agg_lsm_kernel(const float* __restrict__ T, const float* __restrict__ dinv,
                               const int* __restrict__ offsets, const int* __restrict__ csr_src,
                               const float* __restrict__ b4, float* __restrict__ out, int n) {
    int idx = blockIdx.x * blockDim.x + threadIdx.x;
    int node = idx >> 4;
    int lane = idx & 15;
    if (node >= n) return;
    bool act = lane < 10;
    float acc = act ? T[(size_t)node * 10 + lane] : 0.0f;  // self (prescaled)
    int s = offsets[node], e = offsets[node + 1];
    int j = s;
    for (; j + 1 < e; j += 2) {
        int u0 = csr_src[j], u1 = csr_src[j + 1];
        float t0 = act ? T[(size_t)u0 * 10 + lane] : 0.0f;
        float t1 = act ? T[(size_t)u1 * 10 + lane] : 0.0f;
        acc += t0 + t1;
    }
    if (j < e) {
        int u = csr_src[j];
        if (act) acc += T[(size_t)u * 10 + lane];
    }
    float v = act ? fmaf(dinv[node], acc, b4[lane]) : -1e30f;
    float m = v;
#pragma unroll
    for (int d = 1; d < 16; d <<= 1) m = fmaxf(m, __shfl_xor(m, d));
    float ex = act ? expf(v - m) : 0.0f;
    float sum = ex;
#pragma unroll
    for (int d = 1; d < 16; d <<= 1) sum += __shfl_xor(sum, d);
    if (act) out[(size_t)node * 10 + lane] = v - m - logf(sum);
}

// ---------------- BN + GELU ----------------

// In-place BN (batch stats) + exact GELU; optional prescale by dinv (next-agg fusion).
template <int F, bool DINV>
__global__ void bn_gelu_kernel(float* __restrict__ V, const float* __restrict__ stats,
                               const float* __restrict__ g, const float* __restrict__ be,
                               const float* __restrict__ dinv, int n) {
    int i = blockIdx.x * blockDim.x + threadIdx.x;
    if (i >= n * F) return;
    int f = i % F;
    float inv_n = 1.0f / (float)n;
    float mu = stats[f] * inv_n;
    float var = stats[F + f] * inv_n - mu * mu;
    float sc = rsqrtf(var + BN_EPS) * g[f];
    float shf = be[f] - mu * sc;
    float x = fmaf(V[i], sc, shf);
    float y = 0.5f * x * (1.0f + erff(x * 0.70710678118654752f));
    V[i] = DINV ? y * dinv[i / F] : y;
}

static inline int cdiv(long long a, int b) { return (int)((a + b - 1) / b); }

extern "C" void kernel_launch(void* const* d_in, const int* in_sizes, int n_in,
                              void* d_out, int out_size, void* d_ws, size_t ws_size,
                              hipStream_t stream) {
    const float* x  = (const float*)d_in[0];
    const int*   ei = (const int*)d_in[1];
    const float* W1 = (const float*)d_in[2];
    const float* g1 = (const float*)d_in[4];
    const float* be1= (const float*)d_in[5];
    const float* W2 = (const float*)d_in[6];
    const float* g2 = (const float*)d_in[8];
    const float* be2= (const float*)d_in[9];
    const float* W3 = (const float*)d_in[10];
    const float* g3 = (const float*)d_in[12];
    const float* be3= (const float*)d_in[13];
    const float* W4 = (const float*)d_in[14];
    const float* b4 = (const float*)d_in[15];
    float* out = (float*)d_out;

    const int N = in_sizes[0] / 128;
    const int E = in_sizes[1] / 2;
    const int* srcI = ei;
    const int* dstI = ei + E;
    const int NBc = cdiv(E, CCHUNK);           // edge chunks
    const int HN  = K_BUCK * NBc;              // histogram entries
    const int NBh = cdiv(HN, SCHUNK);          // scan blocks for hist

    char* p = (char*)d_ws;
    auto carve = [&](size_t bytes) {
        void* q = (void*)p;
        p += (bytes + 255) & ~(size_t)255;
        return q;
    };
    int*   offsets = (int*)  carve((size_t)(N + 1) * 4);
    float* dinv    = (float*)carve((size_t)N * 4);
    int*   csr_src = (int*)  carve((size_t)E * 4);
    int*   hist    = (int*)  carve((size_t)HN * 4);
    int*   hbase   = (int*)  carve((size_t)(HN + 1) * 4);
    int2*  ebuf    = (int2*) carve((size_t)E * 8);
    int*   bsum    = (int*)  carve((size_t)(NBh + 1) * 4);
    float* stats   = (float*)carve(384 * 4);   // L1@0 (2x16), L2@128 (2x32), L3@256 (2x64)
    float* A       = (float*)carve((size_t)N * 64 * 4);
    float* B       = (float*)carve((size_t)N * 64 * 4);

    // --- bucket-sort CSR build (coalesced writes; no global atomics) ---
    bucket_hist_kernel<<<NBc, TPB, 0, stream>>>(dstI, hist, stats, E, N, NBc);
    scan_reduce_kernel<<<NBh, TPB, 0, stream>>>(hist, bsum, HN);
    scan_bsum_kernel<<<1, 64, 0, stream>>>(bsum, NBh);
    scan_apply_kernel<<<NBh, TPB, 0, stream>>>(hist, bsum, hbase, HN);
    bucket_scatter_kernel<<<NBc, TPB, 0, stream>>>(srcI, dstI, hist, hbase, ebuf, E, N, NBc);
    bucket_offsets_kernel<<<K_BUCK, TPB, 0, stream>>>(ebuf, hbase, offsets, dinv, E, N, NBc);
    csr_fill_kernel<<<K_BUCK, TPB, 0, stream>>>(ebuf, hbase, offsets, csr_src, E, N, NBc);

    // --- L1: transform(128->16, prescaled) then aggregate(16) [stats fused] ---
    gemm_kernel<128, 16, false, true><<<2048, TPB, 0, stream>>>(x, W1, A, nullptr, dinv, N);
    agg4_kernel<16, true><<<1024, TPB, 0, stream>>>(A, B, dinv, offsets, csr_src, stats + 0, N);
    bn_gelu_kernel<16, true><<<cdiv((long long)N * 16, TPB), TPB, 0, stream>>>(B, stats + 0, g1, be1, dinv, N);

    // --- L2: aggregate(16) then transform(16->32) [stats fused into gemm] ---
    agg4_kernel<16, false><<<cdiv((long long)N * 4, TPB), TPB, 0, stream>>>(B, A, dinv, offsets, csr_src, nullptr, N);
    gemm_kernel<16, 32, true, false><<<1024, TPB, 0, stream>>>(A, W2, B, stats + 128, nullptr, N);
    bn_gelu_kernel<32, true><<<cdiv((long long)N * 32, TPB), TPB, 0, stream>>>(B, stats + 128, g2, be2, dinv, N);

    // --- L3: aggregate(32) then transform(32->64) [stats fused into gemm] ---
    agg4_kernel<32, false><<<cdiv((long long)N * 8, TPB), TPB, 0, stream>>>(B, A, dinv, offsets, csr_src, nullptr, N);
    gemm_kernel<32, 64, true, false><<<1024, TPB, 0, stream>>>(A, W3, B, stats + 256, nullptr, N);
    bn_gelu_kernel<64, false><<<cdiv((long long)N * 64, TPB), TPB, 0, stream>>>(B, stats + 256, g3, be3, nullptr, N);

    // --- L4: transform(64->10, prescaled) then aggregate(10)+b4+log_softmax ---
    gemm_kernel<64, 10, false, true><<<1024, TPB, 0, stream>>>(B, W4, A, nullptr, dinv, N);
    agg_lsm_kernel<<<cdiv((long long)N * 16, TPB), TPB, 0, stream>>>(A, dinv, offsets, csr_src, b4, out, N);
}